// Round 2
// baseline (8419.514 us; speedup 1.0000x reference)
//
#include <hip/hip_runtime.h>

#define N_NODES 100000
#define N_EDGES 3200000
#define N_B 64
#define N_CLS 40

// ---------------------------------------------------------------------------
// Layer 1 per-node precompute:
//   A[n][c] = sum_d pos[n][d]*(W11[c][d] + W11[c][3+d]) + b11[c]
//   C[n][c] = -sum_d pos[n][d]*W11[c][3+d]
// ---------------------------------------------------------------------------
__global__ __launch_bounds__(256) void node1_kernel(
    const float* __restrict__ pos, const float* __restrict__ W11,
    const float* __restrict__ b11, float* __restrict__ A, float* __restrict__ C) {
  int n = blockIdx.x * 256 + threadIdx.x;
  if (n >= N_NODES) return;
  float p0 = pos[n * 3 + 0], p1 = pos[n * 3 + 1], p2 = pos[n * 3 + 2];
#pragma unroll
  for (int c = 0; c < 32; ++c) {
    float wa0 = W11[c * 6 + 0], wa1 = W11[c * 6 + 1], wa2 = W11[c * 6 + 2];
    float wp0 = W11[c * 6 + 3], wp1 = W11[c * 6 + 4], wp2 = W11[c * 6 + 5];
    float cp = p0 * wp0 + p1 * wp1 + p2 * wp2;
    A[(size_t)n * 32 + c] = p0 * wa0 + p1 * wa1 + p2 * wa2 + cp + b11[c];
    C[(size_t)n * 32 + c] = -cp;
  }
}

// ---------------------------------------------------------------------------
// Edge kernel: z = A[src] + C[dst]; r = relu(z); m = r @ W2^T + b2;
// scatter-max of max(m,0) into agg[dst] via uint atomicMax (all values >= 0).
// ---------------------------------------------------------------------------
__global__ __launch_bounds__(256) void edge_kernel(
    const int* __restrict__ ei, const float* __restrict__ A,
    const float* __restrict__ C, const float* __restrict__ W2,
    const float* __restrict__ b2, unsigned* __restrict__ agg) {
  __shared__ float Wl[1024];
  __shared__ float bl[32];
  for (int i = threadIdx.x; i < 1024; i += 256) Wl[i] = W2[i];
  if (threadIdx.x < 32) bl[threadIdx.x] = b2[threadIdx.x];
  __syncthreads();

  int e = blockIdx.x * 256 + threadIdx.x;
  if (e >= N_EDGES) return;
  int s = ei[e];
  int d = ei[N_EDGES + e];

  float r[32];
  const float4* Ap = reinterpret_cast<const float4*>(A + (size_t)s * 32);
  const float4* Cp = reinterpret_cast<const float4*>(C + (size_t)d * 32);
#pragma unroll
  for (int q = 0; q < 8; ++q) {
    float4 a = Ap[q];
    float4 c = Cp[q];
    r[4 * q + 0] = fmaxf(a.x + c.x, 0.f);
    r[4 * q + 1] = fmaxf(a.y + c.y, 0.f);
    r[4 * q + 2] = fmaxf(a.z + c.z, 0.f);
    r[4 * q + 3] = fmaxf(a.w + c.w, 0.f);
  }

  unsigned* ag = agg + (size_t)d * 32;
#pragma unroll
  for (int co = 0; co < 32; ++co) {
    float m = bl[co];
    const float4* wr = reinterpret_cast<const float4*>(Wl + co * 32);
#pragma unroll
    for (int q = 0; q < 8; ++q) {
      float4 w = wr[q];
      m = fmaf(r[4 * q + 0], w.x, m);
      m = fmaf(r[4 * q + 1], w.y, m);
      m = fmaf(r[4 * q + 2], w.z, m);
      m = fmaf(r[4 * q + 3], w.w, m);
    }
    atomicMax(ag + co, __float_as_uint(fmaxf(m, 0.f)));
  }
}

// ---------------------------------------------------------------------------
// Layer 2 per-node precompute from h1 (= relu'd layer-1 aggregation) and pos:
//   A2[n][c] = sum_k h1[n][k]*W21[c][k] + sum_d pos[n][d]*W21[c][32+d] + b21[c]
//   C2[n][c] = -sum_d pos[n][d]*W21[c][32+d]
// ---------------------------------------------------------------------------
__global__ __launch_bounds__(256) void node2_kernel(
    const float* __restrict__ h1, const float* __restrict__ pos,
    const float* __restrict__ W21, const float* __restrict__ b21,
    float* __restrict__ A, float* __restrict__ C) {
  __shared__ float Wl[32 * 35];
  __shared__ float bl[32];
  for (int i = threadIdx.x; i < 32 * 35; i += 256) Wl[i] = W21[i];
  if (threadIdx.x < 32) bl[threadIdx.x] = b21[threadIdx.x];
  __syncthreads();

  int n = blockIdx.x * 256 + threadIdx.x;
  if (n >= N_NODES) return;

  float h[32];
  const float4* hp = reinterpret_cast<const float4*>(h1 + (size_t)n * 32);
#pragma unroll
  for (int q = 0; q < 8; ++q) {
    float4 v = hp[q];
    h[4 * q + 0] = v.x; h[4 * q + 1] = v.y;
    h[4 * q + 2] = v.z; h[4 * q + 3] = v.w;
  }
  float p0 = pos[n * 3 + 0], p1 = pos[n * 3 + 1], p2 = pos[n * 3 + 2];
#pragma unroll 4
  for (int co = 0; co < 32; ++co) {
    const float* wr = Wl + co * 35;
    float acc = bl[co];
#pragma unroll
    for (int k = 0; k < 32; ++k) acc = fmaf(h[k], wr[k], acc);
    float cp = p0 * wr[32] + p1 * wr[33] + p2 * wr[34];
    A[(size_t)n * 32 + co] = acc + cp;
    C[(size_t)n * 32 + co] = -cp;
  }
}

// ---------------------------------------------------------------------------
// Global max pool: thread i -> node n = i/32, channel c = i%32.
// ---------------------------------------------------------------------------
__global__ __launch_bounds__(256) void pool_kernel(
    const float* __restrict__ h2, const int* __restrict__ batch,
    unsigned* __restrict__ g) {
  int i = blockIdx.x * 256 + threadIdx.x;
  if (i >= N_NODES * 32) return;
  int n = i >> 5;
  int c = i & 31;
  int b = batch[n];
  atomicMax(g + b * 32 + c, __float_as_uint(h2[i]));
}

// ---------------------------------------------------------------------------
// Classifier: out[b][k] = g[b] . Wc[k] + bc[k]
// ---------------------------------------------------------------------------
__global__ __launch_bounds__(256) void cls_kernel(
    const float* __restrict__ g, const float* __restrict__ Wc,
    const float* __restrict__ bc, float* __restrict__ out) {
  int i = blockIdx.x * 256 + threadIdx.x;
  if (i >= N_B * N_CLS) return;
  int b = i / N_CLS;
  int k = i % N_CLS;
  float acc = bc[k];
#pragma unroll
  for (int c = 0; c < 32; ++c) acc = fmaf(g[b * 32 + c], Wc[k * 32 + c], acc);
  out[i] = acc;
}

extern "C" void kernel_launch(void* const* d_in, const int* in_sizes, int n_in,
                              void* d_out, int out_size, void* d_ws, size_t ws_size,
                              hipStream_t stream) {
  const float* pos = (const float*)d_in[0];
  const int* ei    = (const int*)d_in[1];
  const int* batch = (const int*)d_in[2];
  const float* W11 = (const float*)d_in[3];
  const float* b11 = (const float*)d_in[4];
  const float* W12 = (const float*)d_in[5];
  const float* b12 = (const float*)d_in[6];
  const float* W21 = (const float*)d_in[7];
  const float* b21 = (const float*)d_in[8];
  const float* W22 = (const float*)d_in[9];
  const float* b22 = (const float*)d_in[10];
  const float* Wc  = (const float*)d_in[11];
  const float* bc  = (const float*)d_in[12];
  float* out = (float*)d_out;

  float* ws = (float*)d_ws;
  float* A    = ws;                 // N*32 floats
  float* C    = ws + 3200000;       // N*32
  float* agg1 = ws + 6400000;       // N*32
  float* agg2 = ws + 9600000;       // N*32
  float* g    = ws + 12800000;      // B*32 = 2048

  // zero agg1, agg2, g (contiguous)
  hipMemsetAsync(agg1, 0, (size_t)(6400000 + 2048) * sizeof(float), stream);

  int nb_nodes = (N_NODES + 255) / 256;
  int nb_edges = (N_EDGES + 255) / 256;

  node1_kernel<<<nb_nodes, 256, 0, stream>>>(pos, W11, b11, A, C);
  edge_kernel<<<nb_edges, 256, 0, stream>>>(ei, A, C, W12, b12, (unsigned*)agg1);
  node2_kernel<<<nb_nodes, 256, 0, stream>>>(agg1, pos, W21, b21, A, C);
  edge_kernel<<<nb_edges, 256, 0, stream>>>(ei, A, C, W22, b22, (unsigned*)agg2);
  pool_kernel<<<(N_NODES * 32 + 255) / 256, 256, 0, stream>>>(agg2, batch, (unsigned*)g);
  cls_kernel<<<(N_B * N_CLS + 255) / 256, 256, 0, stream>>>(g, Wc, bc, out);
}